// Round 3
// baseline (412.512 us; speedup 1.0000x reference)
//
#include <hip/hip_runtime.h>

// Problem constants (match reference)
constexpr int NN = 100000;   // nodes
constexpr int NE = 1250000;  // edges
constexpr int D  = 64;       // in == out dim
constexpr int NB = 16;       // bases
constexpr int NBLK = (NN + 255) / 256;   // 391 scan blocks

__device__ __forceinline__ unsigned short f2bf(float f) {
    unsigned u = __float_as_uint(f);
    u += 0x7fffu + ((u >> 16) & 1u);     // round-to-nearest-even
    return (unsigned short)(u >> 16);
}
__device__ __forceinline__ float bf2f(unsigned short h) {
    return __uint_as_float(((unsigned)h) << 16);
}

// ---------------------------------------------------------------------------
// Kernel 1 (fused prep): combine bases -> W,B | zero counts | cast x -> bf16
// thread ranges: [0,8320) combine, [8320,8320+NN) zero, rest: cast (float4 each)
// ---------------------------------------------------------------------------
constexpr int PRE_COMBINE = 8192 + 128;            // 8320
constexpr int PRE_ZERO_END = PRE_COMBINE + NN;     // 108320
constexpr int PRE_TOTAL = PRE_ZERO_END + NN * (D / 4);  // + 1.6M cast tasks

__global__ void prep_kernel(const float* __restrict__ wm,
                            const float* __restrict__ bm,
                            const float* __restrict__ wsf,
                            const float* __restrict__ bsf,
                            const float* __restrict__ lc,
                            const float* __restrict__ x,
                            float* __restrict__ W,   // [8192]: W_msg | W_self
                            float* __restrict__ B,   // [128]:  b_msg | b_self
                            int* __restrict__ counts,
                            unsigned short* __restrict__ xb)
{
    int t = blockIdx.x * blockDim.x + threadIdx.x;
    if (t >= PRE_ZERO_END) {
        // cast 4 floats -> 4 bf16
        int k = t - PRE_ZERO_END;                  // [0, NN*16)
        float4 v = reinterpret_cast<const float4*>(x)[k];
        ushort4 o;
        o.x = f2bf(v.x); o.y = f2bf(v.y); o.z = f2bf(v.z); o.w = f2bf(v.w);
        reinterpret_cast<ushort4*>(xb)[k] = o;
    } else if (t >= PRE_COMBINE) {
        counts[t - PRE_COMBINE] = 0;
    } else {
        float c[NB];
        #pragma unroll
        for (int b = 0; b < NB; ++b) c[b] = lc[b];
        const float* p;
        float* dst;
        if (t < 4096)      { p = wm  + t * NB;            dst = W + t; }
        else if (t < 8192) { p = wsf + (t - 4096) * NB;   dst = W + t; }
        else if (t < 8256) { p = bm  + (t - 8192) * NB;   dst = B + (t - 8192); }
        else               { p = bsf + (t - 8256) * NB;   dst = B + 64 + (t - 8256); }
        float s = 0.f;
        #pragma unroll
        for (int b = 0; b < NB; ++b) s += p[b] * c[b];
        *dst = s;
    }
}

// ---------------------------------------------------------------------------
// Kernel 2: histogram of destination nodes
// ---------------------------------------------------------------------------
__global__ void hist_kernel(const int* __restrict__ ei, int* __restrict__ counts)
{
    int e = blockIdx.x * blockDim.x + threadIdx.x;
    if (e < NE) atomicAdd(&counts[ei[NE + e]], 1);
}

// ---------------------------------------------------------------------------
// Kernels 3a/3b/3c: exclusive prefix sum of counts -> offs
// ---------------------------------------------------------------------------
__global__ void scan_block(const int* __restrict__ counts,
                           int* __restrict__ offs,
                           int* __restrict__ partials)
{
    __shared__ int tmp[256];
    int tid = threadIdx.x;
    int i = blockIdx.x * 256 + tid;
    int c = (i < NN) ? counts[i] : 0;
    int v = c;
    tmp[tid] = v;
    __syncthreads();
    for (int off = 1; off < 256; off <<= 1) {
        int t = (tid >= off) ? tmp[tid - off] : 0;
        __syncthreads();
        v += t;
        tmp[tid] = v;
        __syncthreads();
    }
    if (i < NN) offs[i] = v - c;
    if (tid == 255) partials[blockIdx.x] = v;
}

__global__ void scan_partials(int* __restrict__ partials)
{
    __shared__ int tmp[512];
    int tid = threadIdx.x;
    int c = (tid < NBLK) ? partials[tid] : 0;
    int v = c;
    tmp[tid] = v;
    __syncthreads();
    for (int off = 1; off < 512; off <<= 1) {
        int t = (tid >= off) ? tmp[tid - off] : 0;
        __syncthreads();
        v += t;
        tmp[tid] = v;
        __syncthreads();
    }
    if (tid < NBLK) partials[tid] = v - c;
}

__global__ void add_offsets(int* __restrict__ offs, const int* __restrict__ partials)
{
    int i = blockIdx.x * 256 + threadIdx.x;
    if (i < NN) offs[i] += partials[blockIdx.x];
}

// ---------------------------------------------------------------------------
// Kernel 4: bucket-scatter src ids into CSR order (offs becomes end offsets)
// ---------------------------------------------------------------------------
__global__ void scatter_sort(const int* __restrict__ ei,
                             int* __restrict__ offs,
                             int* __restrict__ sorted_src)
{
    int e = blockIdx.x * blockDim.x + threadIdx.x;
    if (e >= NE) return;
    int src = ei[e];
    int dst = ei[NE + e];
    int pos = atomicAdd(&offs[dst], 1);
    sorted_src[pos] = src;
}

// ---------------------------------------------------------------------------
// Kernel 5: gather-sum bf16 x rows into agg (= d_out). One wave per node.
// No LDS, low VGPR -> high occupancy; 8 accumulators for deep MLP.
// ---------------------------------------------------------------------------
__global__ __launch_bounds__(256)
void gather_kernel(const unsigned short* __restrict__ xb,
                   const int* __restrict__ sorted_src,
                   const int* __restrict__ offs,     // end offsets
                   const int* __restrict__ counts,
                   float* __restrict__ agg)
{
    const int wave = threadIdx.x >> 6;
    const int lane = threadIdx.x & 63;
    const int n = blockIdx.x * 4 + wave;   // 25000 * 4 == NN exactly

    const int deg = counts[n];
    const int end = offs[n];
    int j = end - deg;

    float a0 = 0.f, a1 = 0.f, a2 = 0.f, a3 = 0.f;
    float a4 = 0.f, a5 = 0.f, a6 = 0.f, a7 = 0.f;
    for (; j + 8 <= end; j += 8) {
        int s0 = sorted_src[j + 0];
        int s1 = sorted_src[j + 1];
        int s2 = sorted_src[j + 2];
        int s3 = sorted_src[j + 3];
        int s4 = sorted_src[j + 4];
        int s5 = sorted_src[j + 5];
        int s6 = sorted_src[j + 6];
        int s7 = sorted_src[j + 7];
        a0 += bf2f(xb[(size_t)s0 * D + lane]);
        a1 += bf2f(xb[(size_t)s1 * D + lane]);
        a2 += bf2f(xb[(size_t)s2 * D + lane]);
        a3 += bf2f(xb[(size_t)s3 * D + lane]);
        a4 += bf2f(xb[(size_t)s4 * D + lane]);
        a5 += bf2f(xb[(size_t)s5 * D + lane]);
        a6 += bf2f(xb[(size_t)s6 * D + lane]);
        a7 += bf2f(xb[(size_t)s7 * D + lane]);
    }
    for (; j + 4 <= end; j += 4) {
        int s0 = sorted_src[j + 0];
        int s1 = sorted_src[j + 1];
        int s2 = sorted_src[j + 2];
        int s3 = sorted_src[j + 3];
        a0 += bf2f(xb[(size_t)s0 * D + lane]);
        a1 += bf2f(xb[(size_t)s1 * D + lane]);
        a2 += bf2f(xb[(size_t)s2 * D + lane]);
        a3 += bf2f(xb[(size_t)s3 * D + lane]);
    }
    for (; j < end; ++j) a0 += bf2f(xb[(size_t)sorted_src[j] * D + lane]);

    agg[(size_t)n * D + lane] = ((a0 + a1) + (a2 + a3)) + ((a4 + a5) + (a6 + a7));
}

// ---------------------------------------------------------------------------
// Kernel 6: transform + normalize (in place over d_out).
// out = normalize( agg @ W_msg + deg*b_msg + x @ W_self + b_self )
// ---------------------------------------------------------------------------
__global__ __launch_bounds__(256)
void transform_kernel(const float* __restrict__ x,
                      float* __restrict__ out,        // agg in, result out
                      const int* __restrict__ counts,
                      const float* __restrict__ W,    // [8192]
                      const float* __restrict__ B)    // [128]
{
    __shared__ float sW[2 * 4096];
    __shared__ float sB[128];
    for (int i = threadIdx.x; i < 8192; i += 256) sW[i] = W[i];
    if (threadIdx.x < 128) sB[threadIdx.x] = B[threadIdx.x];
    __syncthreads();

    const int wave = threadIdx.x >> 6;
    const int lane = threadIdx.x & 63;
    const int n = blockIdx.x * 4 + wave;

    float av = out[(size_t)n * D + lane];   // agg row (read before write)
    float xv = x[(size_t)n * D + lane];
    float dg = (float)counts[n];

    float acc = dg * sB[lane] + sB[64 + lane];
    #pragma unroll 8
    for (int i = 0; i < D; ++i) {
        float ai = __shfl(av, i, 64);
        float xi = __shfl(xv, i, 64);
        acc += ai * sW[i * D + lane] + xi * sW[4096 + i * D + lane];
    }

    float s = acc * acc;
    #pragma unroll
    for (int off = 32; off; off >>= 1) s += __shfl_xor(s, off, 64);
    float norm = sqrtf(s);

    out[(size_t)n * D + lane] = acc / fmaxf(norm, 1e-12f);
}

// ---------------------------------------------------------------------------
extern "C" void kernel_launch(void* const* d_in, const int* in_sizes, int n_in,
                              void* d_out, int out_size, void* d_ws, size_t ws_size,
                              hipStream_t stream)
{
    const float* x   = (const float*)d_in[0];
    const int*   ei  = (const int*)d_in[1];
    const float* wm  = (const float*)d_in[2];
    const float* bm  = (const float*)d_in[3];
    const float* wsf = (const float*)d_in[4];
    const float* bsf = (const float*)d_in[5];
    const float* lc  = (const float*)d_in[6];

    float* out = (float*)d_out;

    // ws layout (4B units unless noted):
    // W[8192] | B[128] | counts[NN] | offs[NN] | partials[512] | sorted_src[NE] | xb[NN*D ushorts]
    float* W        = (float*)d_ws;
    float* Bv       = W + 8192;
    int*   counts   = (int*)(Bv + 128);
    int*   offs     = counts + NN;
    int*   partials = offs + NN;
    int*   sorted_src = partials + 512;
    unsigned short* xb = (unsigned short*)(sorted_src + NE);

    // 1. combine bases + zero counts + cast x->bf16 (fused)
    prep_kernel<<<(PRE_TOTAL + 255) / 256, 256, 0, stream>>>(
        wm, bm, wsf, bsf, lc, x, W, Bv, counts, xb);

    // 2. histogram of dst
    hist_kernel<<<(NE + 255) / 256, 256, 0, stream>>>(ei, counts);

    // 3. exclusive scan -> offs
    scan_block<<<NBLK, 256, 0, stream>>>(counts, offs, partials);
    scan_partials<<<1, 512, 0, stream>>>(partials);
    add_offsets<<<NBLK, 256, 0, stream>>>(offs, partials);

    // 4. bucket-scatter src ids
    scatter_sort<<<(NE + 255) / 256, 256, 0, stream>>>(ei, offs, sorted_src);

    // 5. gather-sum bf16 rows -> agg (in d_out)
    gather_kernel<<<NN / 4, 256, 0, stream>>>(xb, sorted_src, offs, counts, out);

    // 6. transform + normalize (in place)
    transform_kernel<<<NN / 4, 256, 0, stream>>>(x, out, counts, W, Bv);
}

// Round 5
// 221.768 us; speedup vs baseline: 1.8601x; 1.8601x over previous
//
#include <hip/hip_runtime.h>

// Problem constants (match reference)
constexpr int NN = 100000;   // nodes
constexpr int NE = 1250000;  // edges
constexpr int D  = 64;       // in == out dim
constexpr int NB = 16;       // bases
constexpr int NBLK = (NN + 255) / 256;   // 391 scan blocks

typedef __attribute__((ext_vector_type(8))) short short8v;   // 8 bf16 (4 VGPR)
typedef __attribute__((ext_vector_type(4))) float float4v;

__device__ __forceinline__ unsigned short f2bf(float f) {
    unsigned u = __float_as_uint(f);
    u += 0x7fffu + ((u >> 16) & 1u);     // round-to-nearest-even
    return (unsigned short)(u >> 16);
}
__device__ __forceinline__ float bf2f(unsigned short h) {
    return __uint_as_float(((unsigned)h) << 16);
}

// ---------------------------------------------------------------------------
// Kernel 1 (fused prep): combine bases -> WcT(bf16),B | zero counts | cast x->bf16
// WcT layout: [o][k] bf16, k = i for W_msg (k<64), k = 64+i for W_self.
// ---------------------------------------------------------------------------
constexpr int PRE_COMBINE = 8192 + 128;            // 8320
constexpr int PRE_ZERO_END = PRE_COMBINE + NN;     // 108320
constexpr int PRE_TOTAL = PRE_ZERO_END + NN * (D / 4);

__global__ void prep_kernel(const float* __restrict__ wm,
                            const float* __restrict__ bm,
                            const float* __restrict__ wsf,
                            const float* __restrict__ bsf,
                            const float* __restrict__ lc,
                            const float* __restrict__ x,
                            unsigned short* __restrict__ wct, // [64*128] bf16
                            float* __restrict__ B,            // [128] fp32
                            int* __restrict__ counts,
                            unsigned short* __restrict__ xb)
{
    int t = blockIdx.x * blockDim.x + threadIdx.x;
    if (t >= PRE_ZERO_END) {
        if (t < PRE_TOTAL) {                       // BOUND: tail threads must not write
            int k = t - PRE_ZERO_END;              // [0, NN*16)
            float4 v = reinterpret_cast<const float4*>(x)[k];
            ushort4 o;
            o.x = f2bf(v.x); o.y = f2bf(v.y); o.z = f2bf(v.z); o.w = f2bf(v.w);
            reinterpret_cast<ushort4*>(xb)[k] = o;
        }
    } else if (t >= PRE_COMBINE) {
        counts[t - PRE_COMBINE] = 0;
    } else {
        float c[NB];
        #pragma unroll
        for (int b = 0; b < NB; ++b) c[b] = lc[b];
        const float* p;
        if (t < 4096)      p = wm  + t * NB;
        else if (t < 8192) p = wsf + (t - 4096) * NB;
        else if (t < 8256) p = bm  + (t - 8192) * NB;
        else               p = bsf + (t - 8256) * NB;
        float s = 0.f;
        #pragma unroll
        for (int b = 0; b < NB; ++b) s += p[b] * c[b];

        if (t < 4096) {                       // W_msg[i][o] -> wct[o][i]
            int i = t >> 6, o = t & 63;
            wct[o * 128 + i] = f2bf(s);
        } else if (t < 8192) {                // W_self[i][o] -> wct[o][64+i]
            int u = t - 4096;
            int i = u >> 6, o = u & 63;
            wct[o * 128 + 64 + i] = f2bf(s);
        } else if (t < 8256) {
            B[t - 8192] = s;                  // b_msg
        } else {
            B[64 + (t - 8256)] = s;           // b_self
        }
    }
}

// ---------------------------------------------------------------------------
// Kernel 2: histogram of destination nodes
// ---------------------------------------------------------------------------
__global__ void hist_kernel(const int* __restrict__ ei, int* __restrict__ counts)
{
    int e = blockIdx.x * blockDim.x + threadIdx.x;
    if (e < NE) atomicAdd(&counts[ei[NE + e]], 1);
}

// ---------------------------------------------------------------------------
// Kernels 3a/3b/3c: exclusive prefix sum of counts -> offs
// ---------------------------------------------------------------------------
__global__ void scan_block(const int* __restrict__ counts,
                           int* __restrict__ offs,
                           int* __restrict__ partials)
{
    __shared__ int tmp[256];
    int tid = threadIdx.x;
    int i = blockIdx.x * 256 + tid;
    int c = (i < NN) ? counts[i] : 0;
    int v = c;
    tmp[tid] = v;
    __syncthreads();
    for (int off = 1; off < 256; off <<= 1) {
        int t = (tid >= off) ? tmp[tid - off] : 0;
        __syncthreads();
        v += t;
        tmp[tid] = v;
        __syncthreads();
    }
    if (i < NN) offs[i] = v - c;
    if (tid == 255) partials[blockIdx.x] = v;
}

__global__ void scan_partials(int* __restrict__ partials)
{
    __shared__ int tmp[512];
    int tid = threadIdx.x;
    int c = (tid < NBLK) ? partials[tid] : 0;
    int v = c;
    tmp[tid] = v;
    __syncthreads();
    for (int off = 1; off < 512; off <<= 1) {
        int t = (tid >= off) ? tmp[tid - off] : 0;
        __syncthreads();
        v += t;
        tmp[tid] = v;
        __syncthreads();
    }
    if (tid < NBLK) partials[tid] = v - c;
}

__global__ void add_offsets(int* __restrict__ offs, const int* __restrict__ partials)
{
    int i = blockIdx.x * 256 + threadIdx.x;
    if (i < NN) offs[i] += partials[blockIdx.x];
}

// ---------------------------------------------------------------------------
// Kernel 4: bucket-scatter src ids into CSR order (offs becomes end offsets)
// ---------------------------------------------------------------------------
__global__ void scatter_sort(const int* __restrict__ ei,
                             int* __restrict__ offs,
                             int* __restrict__ sorted_src)
{
    int e = blockIdx.x * blockDim.x + threadIdx.x;
    if (e >= NE) return;
    int src = ei[e];
    int dst = ei[NE + e];
    int pos = atomicAdd(&offs[dst], 1);
    sorted_src[pos] = src;
}

// ---------------------------------------------------------------------------
// Kernel 5: gather-sum bf16 x rows into agg (= d_out, fp32). One wave per node.
// ---------------------------------------------------------------------------
__global__ __launch_bounds__(256)
void gather_kernel(const unsigned short* __restrict__ xb,
                   const int* __restrict__ sorted_src,
                   const int* __restrict__ offs,     // end offsets
                   const int* __restrict__ counts,
                   float* __restrict__ agg)
{
    const int wave = threadIdx.x >> 6;
    const int lane = threadIdx.x & 63;
    const int n = blockIdx.x * 4 + wave;   // 25000 * 4 == NN exactly

    const int deg = counts[n];
    const int end = offs[n];
    int j = end - deg;

    float a0 = 0.f, a1 = 0.f, a2 = 0.f, a3 = 0.f;
    float a4 = 0.f, a5 = 0.f, a6 = 0.f, a7 = 0.f;
    for (; j + 8 <= end; j += 8) {
        int s0 = sorted_src[j + 0];
        int s1 = sorted_src[j + 1];
        int s2 = sorted_src[j + 2];
        int s3 = sorted_src[j + 3];
        int s4 = sorted_src[j + 4];
        int s5 = sorted_src[j + 5];
        int s6 = sorted_src[j + 6];
        int s7 = sorted_src[j + 7];
        a0 += bf2f(xb[(size_t)s0 * D + lane]);
        a1 += bf2f(xb[(size_t)s1 * D + lane]);
        a2 += bf2f(xb[(size_t)s2 * D + lane]);
        a3 += bf2f(xb[(size_t)s3 * D + lane]);
        a4 += bf2f(xb[(size_t)s4 * D + lane]);
        a5 += bf2f(xb[(size_t)s5 * D + lane]);
        a6 += bf2f(xb[(size_t)s6 * D + lane]);
        a7 += bf2f(xb[(size_t)s7 * D + lane]);
    }
    for (; j + 4 <= end; j += 4) {
        int s0 = sorted_src[j + 0];
        int s1 = sorted_src[j + 1];
        int s2 = sorted_src[j + 2];
        int s3 = sorted_src[j + 3];
        a0 += bf2f(xb[(size_t)s0 * D + lane]);
        a1 += bf2f(xb[(size_t)s1 * D + lane]);
        a2 += bf2f(xb[(size_t)s2 * D + lane]);
        a3 += bf2f(xb[(size_t)s3 * D + lane]);
    }
    for (; j < end; ++j) a0 += bf2f(xb[(size_t)sorted_src[j] * D + lane]);

    agg[(size_t)n * D + lane] = ((a0 + a1) + (a2 + a3)) + ((a4 + a5) + (a6 + a7));
}

// ---------------------------------------------------------------------------
// Kernel 6: MFMA transform + normalize, in place over d_out.
// Per wave: 16-node tile. D[16x64] = A[16x128] @ WcT^T, A = [agg | x] bf16.
// 16x16x32 bf16 MFMA; W frags hoisted in VGPRs (persistent waves, no LDS).
// A-frag: lane row = l&15, k = (l>>4)*8+j.  B-frag: col o = l&15, same k.
// C/D: col = l&15, row = (l>>4)*4 + reg  [m89 verified layout]
// ---------------------------------------------------------------------------
constexpr int NTILES = NN / 16;          // 6250
constexpr int TBLOCKS = 640;             // persistent blocks (2560 waves)

__global__ __launch_bounds__(256)
void transform_mfma(float* __restrict__ out,                 // agg in / out
                    const unsigned short* __restrict__ xb,   // [NN][64] bf16
                    const unsigned short* __restrict__ wct,  // [64][128] bf16
                    const float* __restrict__ B,             // [128] fp32
                    const int* __restrict__ counts)
{
    const int lane = threadIdx.x & 63;
    const int gq = lane >> 4;        // 0..3
    const int c  = lane & 15;
    const int wglob = blockIdx.x * 4 + (threadIdx.x >> 6);

    // Hoist W fragments: wf[otile][ks] — 64 VGPRs
    short8v wf[4][4];
    #pragma unroll
    for (int t = 0; t < 4; ++t)
        #pragma unroll
        for (int ks = 0; ks < 4; ++ks) {
            int o = t * 16 + c;
            int k0 = ks * 32 + gq * 8;
            wf[t][ks] = *reinterpret_cast<const short8v*>(wct + o * 128 + k0);
        }
    // Hoist biases (per-lane o columns)
    float bmv[4], bsv[4];
    #pragma unroll
    for (int t = 0; t < 4; ++t) {
        bmv[t] = B[t * 16 + c];
        bsv[t] = B[64 + t * 16 + c];
    }

    for (int tile = wglob; tile < NTILES; tile += TBLOCKS * 4) {
        const int n0 = tile * 16;
        const size_t arow = (size_t)(n0 + c) * D;   // this lane's A row

        float4v acc[4];
        #pragma unroll
        for (int t = 0; t < 4; ++t) acc[t] = (float4v){0.f, 0.f, 0.f, 0.f};

        // ks = 0,1 : agg (fp32 in out[]) -> bf16 in-register
        #pragma unroll
        for (int ks = 0; ks < 2; ++ks) {
            const float* p = out + arow + ks * 32 + gq * 8;
            float4v f0 = *reinterpret_cast<const float4v*>(p);
            float4v f1 = *reinterpret_cast<const float4v*>(p + 4);
            short8v a;
            a[0] = (short)f2bf(f0[0]); a[1] = (short)f2bf(f0[1]);
            a[2] = (short)f2bf(f0[2]); a[3] = (short)f2bf(f0[3]);
            a[4] = (short)f2bf(f1[0]); a[5] = (short)f2bf(f1[1]);
            a[6] = (short)f2bf(f1[2]); a[7] = (short)f2bf(f1[3]);
            #pragma unroll
            for (int t = 0; t < 4; ++t)
                acc[t] = __builtin_amdgcn_mfma_f32_16x16x32_bf16(a, wf[t][ks], acc[t], 0, 0, 0);
        }
        // ks = 2,3 : x (already bf16)
        #pragma unroll
        for (int ks = 2; ks < 4; ++ks) {
            short8v a = *reinterpret_cast<const short8v*>(xb + arow + (ks - 2) * 32 + gq * 8);
            #pragma unroll
            for (int t = 0; t < 4; ++t)
                acc[t] = __builtin_amdgcn_mfma_f32_16x16x32_bf16(a, wf[t][ks], acc[t], 0, 0, 0);
        }

        // epilogue: bias + deg*b_msg, row L2-norm, in-place write
        float dg[4];
        #pragma unroll
        for (int q = 0; q < 4; ++q) dg[q] = (float)counts[n0 + gq * 4 + q];

        float ss[4] = {0.f, 0.f, 0.f, 0.f};
        #pragma unroll
        for (int t = 0; t < 4; ++t)
            #pragma unroll
            for (int q = 0; q < 4; ++q) {
                float v = acc[t][q] + dg[q] * bmv[t] + bsv[t];
                acc[t][q] = v;
                ss[q] += v * v;
            }
        #pragma unroll
        for (int off = 1; off <= 8; off <<= 1)
            #pragma unroll
            for (int q = 0; q < 4; ++q) ss[q] += __shfl_xor(ss[q], off, 64);

        float sc[4];
        #pragma unroll
        for (int q = 0; q < 4; ++q) sc[q] = 1.f / fmaxf(sqrtf(ss[q]), 1e-12f);

        #pragma unroll
        for (int t = 0; t < 4; ++t)
            #pragma unroll
            for (int q = 0; q < 4; ++q)
                out[(size_t)(n0 + gq * 4 + q) * D + t * 16 + c] = acc[t][q] * sc[q];
    }
}

// ---------------------------------------------------------------------------
extern "C" void kernel_launch(void* const* d_in, const int* in_sizes, int n_in,
                              void* d_out, int out_size, void* d_ws, size_t ws_size,
                              hipStream_t stream)
{
    const float* x   = (const float*)d_in[0];
    const int*   ei  = (const int*)d_in[1];
    const float* wm  = (const float*)d_in[2];
    const float* bm  = (const float*)d_in[3];
    const float* wsf = (const float*)d_in[4];
    const float* bsf = (const float*)d_in[5];
    const float* lc  = (const float*)d_in[6];

    float* out = (float*)d_out;

    // ws layout (4B units unless noted). wct moved BEFORE xb so any overrun
    // past xb lands in dead space, never in live weights.
    // B[128] | wct[8192 ushort = 4096 words] | counts[NN] | offs[NN]
    //   | partials[512] | sorted_src[NE] | xb[NN*64 ushort]
    float* Bv       = (float*)d_ws;
    unsigned short* wct = (unsigned short*)(Bv + 128);
    int*   counts   = (int*)(wct + 8192);
    int*   offs     = counts + NN;
    int*   partials = offs + NN;
    int*   sorted_src = partials + 512;
    unsigned short* xb  = (unsigned short*)(sorted_src + NE);

    // 1. combine bases (-> bf16 WcT) + zero counts + cast x->bf16 (fused)
    prep_kernel<<<(PRE_TOTAL + 255) / 256, 256, 0, stream>>>(
        wm, bm, wsf, bsf, lc, x, wct, Bv, counts, xb);

    // 2. histogram of dst
    hist_kernel<<<(NE + 255) / 256, 256, 0, stream>>>(ei, counts);

    // 3. exclusive scan -> offs
    scan_block<<<NBLK, 256, 0, stream>>>(counts, offs, partials);
    scan_partials<<<1, 512, 0, stream>>>(partials);
    add_offsets<<<NBLK, 256, 0, stream>>>(offs, partials);

    // 4. bucket-scatter src ids
    scatter_sort<<<(NE + 255) / 256, 256, 0, stream>>>(ei, offs, sorted_src);

    // 5. gather-sum bf16 rows -> agg (fp32, in d_out)
    gather_kernel<<<NN / 4, 256, 0, stream>>>(xb, sorted_src, offs, counts, out);

    // 6. MFMA transform + normalize (in place)
    transform_mfma<<<TBLOCKS, 256, 0, stream>>>(out, xb, wct, Bv, counts);
}